// Round 19
// baseline (394.083 us; speedup 1.0000x reference)
//
#include <hip/hip_runtime.h>
#include <math.h>

#define N_NODES 8192
#define N_EDGES 131072

typedef unsigned short u16;
typedef unsigned int u32;
typedef short bf16x8 __attribute__((ext_vector_type(8)));
typedef float f32x4 __attribute__((ext_vector_type(4)));

__device__ __forceinline__ u16 f2bf(float x) {
    unsigned u = __float_as_uint(x);
    u += 0x7fffu + ((u >> 16) & 1u);
    return (u16)(u >> 16);
}
__device__ __forceinline__ float bf2f(u16 h) { return __uint_as_float(((unsigned)h) << 16); }

template <int NU> struct UV;
template <> struct UV<1> { typedef u32 T; };
template <> struct UV<2> { typedef uint2 T; };
template <> struct UV<4> { typedef uint4 T; };

// ---------------- degree / CSR build ----------------

__global__ void k_count(const int* __restrict__ ei, int* __restrict__ deg) {
    int e = blockIdx.x * 256 + threadIdx.x;
    if (e < N_EDGES) atomicAdd(&deg[ei[N_EDGES + e]], 1);
}

__global__ __launch_bounds__(1024) void k_scan(const int* __restrict__ deg,
                                               int* __restrict__ rowptr,
                                               int* __restrict__ pos,
                                               float* __restrict__ dinv) {
    __shared__ int sums[1024];
    int t = threadIdx.x;
    int local[8];
    int s = 0;
#pragma unroll
    for (int i = 0; i < 8; ++i) {
        local[i] = deg[t * 8 + i];
        dinv[t * 8 + i] = 1.0f / sqrtf((float)(local[i] + 1));
        s += local[i];
    }
    sums[t] = s;
    __syncthreads();
    for (int off = 1; off < 1024; off <<= 1) {
        int v = (t >= off) ? sums[t - off] : 0;
        __syncthreads();
        sums[t] += v;
        __syncthreads();
    }
    int run = sums[t] - s;
#pragma unroll
    for (int i = 0; i < 8; ++i) {
        rowptr[t * 8 + i] = run;
        pos[t * 8 + i] = run;
        run += local[i];
    }
    if (t == 1023) rowptr[8192] = run;
}

__global__ void k_fill(const int* __restrict__ ei, const float* __restrict__ dinv,
                       int* __restrict__ pos, int* __restrict__ csr_src,
                       float* __restrict__ csr_w) {
    int e = blockIdx.x * 256 + threadIdx.x;
    if (e < N_EDGES) {
        int s = ei[e];
        int t = ei[N_EDGES + e];
        int idx = atomicAdd(&pos[t], 1);
        csr_src[idx] = s;
        csr_w[idx] = dinv[s] * dinv[t];
    }
}

// ---------------- merged weight prep (+ deg zeroing folded in) ----------------
// fragment-linear global layout per plane: elem B[n][k] stored at
// ((k>>3)*N + n)*8 + (k&7)
__global__ void k_prep_all(const float* __restrict__ g1w, const float* __restrict__ g2w,
                           const float* __restrict__ g3w, const float* __restrict__ d1w,
                           const float* __restrict__ d2w, const float* __restrict__ d3w,
                           u16* __restrict__ wts, int* __restrict__ deg) {
    int idx = blockIdx.x * 256 + threadIdx.x; // < 1376256
    if (idx < N_NODES) deg[idx] = 0;          // folded k_zero_deg (runs before k_count)
    const float* W;
    int local, lgK, N;
    u16 *hi, *lo;
    if (idx < 32768)        { W = g1w; local = idx;           lgK = 7;  N = 256;  hi = wts;           lo = wts + 32768; }
    else if (idx < 163840)  { W = g2w; local = idx - 32768;   lgK = 8;  N = 512;  hi = wts + 65536;   lo = wts + 196608; }
    else if (idx < 688128)  { W = g3w; local = idx - 163840;  lgK = 9;  N = 1024; hi = wts + 327680;  lo = wts + 851968; }
    else if (idx < 1212416) { W = d1w; local = idx - 688128;  lgK = 10; N = 512;  hi = wts + 1376256; lo = wts + 1900544; }
    else if (idx < 1343488) { W = d2w; local = idx - 1212416; lgK = 9;  N = 256;  hi = wts + 2424832; lo = wts + 2555904; }
    else if (idx < 1376256) { W = d3w; local = idx - 1343488; lgK = 8;  N = 128;  hi = wts + 2686976; lo = wts + 2719744; }
    else return;
    int n = local >> lgK;
    int k = local & ((1 << lgK) - 1);
    float v = W[(size_t)k * N + n];
    u16 h = f2bf(v);
    int dst = ((k >> 3) * N + n) * 8 + (k & 7);
    hi[dst] = h;
    lo[dst] = f2bf(v - bf2f(h));
}

// ---------------- fused encoder ----------------
__global__ __launch_bounds__(256) void k_enc_fused(const float* __restrict__ x,
                                                   const float* __restrict__ w1, const float* __restrict__ b1,
                                                   const float* __restrict__ w2, const float* __restrict__ b2,
                                                   const float* __restrict__ w3, const float* __restrict__ b3,
                                                   u16* __restrict__ Chi, u16* __restrict__ Clo) {
    __shared__ float lw[10560];
    const int tid = threadIdx.x;
    for (int i = tid; i < 96; i += 256) lw[i] = w1[i];
    for (int i = tid; i < 32; i += 256) lw[96 + i] = b1[i];
    for (int i = tid; i < 2048; i += 256) lw[128 + i] = w2[i];
    for (int i = tid; i < 64; i += 256) lw[2176 + i] = b2[i];
    for (int i = tid; i < 8192; i += 256) lw[2240 + i] = w3[i];
    for (int i = tid; i < 128; i += 256) lw[10432 + i] = b3[i];
    __syncthreads();

    const int lane = tid & 63;
    const int node = blockIdx.x * 4 + (tid >> 6);

    float x0 = x[node * 3 + 0], x1 = x[node * 3 + 1], x2 = x[node * 3 + 2];

    int o1 = lane & 31;
    float h1 = fmaxf(x0 * lw[o1] + x1 * lw[32 + o1] + x2 * lw[64 + o1] + lw[96 + o1], 0.f);

    float h2 = lw[2176 + lane];
#pragma unroll
    for (int k = 0; k < 32; ++k) h2 += __shfl(h1, k) * lw[128 + k * 64 + lane];
    h2 = fmaxf(h2, 0.f);

    float h3a = lw[10432 + lane];
    float h3b = lw[10432 + 64 + lane];
#pragma unroll
    for (int k = 0; k < 64; ++k) {
        float hk = __shfl(h2, k);
        h3a += hk * lw[2240 + k * 128 + lane];
        h3b += hk * lw[2240 + k * 128 + 64 + lane];
    }
    h3a = fmaxf(h3a, 0.f);
    h3b = fmaxf(h3b, 0.f);

    size_t base = (size_t)node * 128;
    u16 ha = f2bf(h3a), hb = f2bf(h3b);
    Chi[base + lane] = ha;
    Chi[base + 64 + lane] = hb;
    Clo[base + lane] = f2bf(h3a - bf2f(ha));
    Clo[base + 64 + lane] = f2bf(h3b - bf2f(hb));
}

// ---------------- fused d4 (128 -> 50) + softmax ----------------
__global__ __launch_bounds__(256) void k_d4sm_fused(const float* __restrict__ A,
                                                    const float* __restrict__ W,
                                                    const float* __restrict__ bias,
                                                    float* __restrict__ out) {
    __shared__ float lw[6450];
    const int tid = threadIdx.x;
    for (int i = tid; i < 6400; i += 256) lw[i] = W[i];
    for (int i = tid; i < 50; i += 256) lw[6400 + i] = bias[i];
    __syncthreads();

    const int lane = tid & 63;
    const int node = blockIdx.x * 4 + (tid >> 6);

    float a0 = A[(size_t)node * 128 + lane];
    float a1 = A[(size_t)node * 128 + 64 + lane];

    float acc = (lane < 50) ? lw[6400 + lane] : 0.f;
    int oc = (lane < 50) ? lane : 0;
#pragma unroll
    for (int k = 0; k < 64; ++k) acc += __shfl(a0, k) * lw[k * 50 + oc];
#pragma unroll
    for (int k = 0; k < 64; ++k) acc += __shfl(a1, k) * lw[(64 + k) * 50 + oc];

    float v = (lane < 50) ? acc : -INFINITY;
    float m = v;
#pragma unroll
    for (int off = 32; off; off >>= 1) m = fmaxf(m, __shfl_xor(m, off));
    float e = (lane < 50) ? expf(v - m) : 0.f;
    float s = e;
#pragma unroll
    for (int off = 32; off; off >>= 1) s += __shfl_xor(s, off);
    if (lane < 50) out[(size_t)node * 50 + lane] = e / s;
}

// ---------------- aggregation on split bf16 planes ----------------
template <int D>
__global__ __launch_bounds__(256) void k_agg_s(const u16* __restrict__ hi_in,
                                               const u16* __restrict__ lo_in,
                                               u16* __restrict__ hi_out,
                                               u16* __restrict__ lo_out,
                                               const int* __restrict__ rowptr,
                                               const int* __restrict__ csr_src,
                                               const float* __restrict__ csr_w,
                                               const float* __restrict__ dinv) {
    constexpr int EPL = D / 64;
    constexpr int NU = EPL / 2;
    using VT = typename UV<NU>::T;
    int node = blockIdx.x * 4 + (threadIdx.x >> 6);
    int lane = threadIdx.x & 63;
    const size_t off = (size_t)node * D + lane * EPL;
    float acc[EPL];
    {
        float dn = dinv[node];
        float w0 = dn * dn;
        u32 hu[NU], lu[NU];
        *(VT*)hu = *(const VT*)(hi_in + off);
        *(VT*)lu = *(const VT*)(lo_in + off);
#pragma unroll
        for (int j = 0; j < NU; ++j) {
            acc[2 * j]     = (__uint_as_float(hu[j] << 16) + __uint_as_float(lu[j] << 16)) * w0;
            acc[2 * j + 1] = (__uint_as_float(hu[j] & 0xffff0000u) + __uint_as_float(lu[j] & 0xffff0000u)) * w0;
        }
    }
#define EDGE_ACC(S, W) do {                                                            \
        size_t so = (size_t)(S) * D + lane * EPL;                                      \
        u32 hu[NU], lu[NU];                                                            \
        *(VT*)hu = *(const VT*)(hi_in + so);                                           \
        *(VT*)lu = *(const VT*)(lo_in + so);                                           \
        _Pragma("unroll")                                                              \
        for (int j = 0; j < NU; ++j) {                                                 \
            acc[2 * j]     += (__uint_as_float(hu[j] << 16) + __uint_as_float(lu[j] << 16)) * (W); \
            acc[2 * j + 1] += (__uint_as_float(hu[j] & 0xffff0000u) + __uint_as_float(lu[j] & 0xffff0000u)) * (W); \
        }                                                                              \
    } while (0)
    int beg = rowptr[node], end = rowptr[node + 1];
    int e = beg;
    for (; e + 2 <= end; e += 2) {
        int s0 = csr_src[e], s1 = csr_src[e + 1];
        float wa = csr_w[e], wb = csr_w[e + 1];
        EDGE_ACC(s0, wa);
        EDGE_ACC(s1, wb);
    }
    if (e < end) EDGE_ACC(csr_src[e], csr_w[e]);
#undef EDGE_ACC
    u32 how[NU], low[NU];
#pragma unroll
    for (int j = 0; j < NU; ++j) {
        u16 h0 = f2bf(acc[2 * j]);     u16 l0 = f2bf(acc[2 * j] - bf2f(h0));
        u16 h1 = f2bf(acc[2 * j + 1]); u16 l1 = f2bf(acc[2 * j + 1] - bf2f(h1));
        how[j] = (u32)h0 | ((u32)h1 << 16);
        low[j] = (u32)l0 | ((u32)l1 << 16);
    }
    *(VT*)(hi_out + off) = *(VT*)how;
    *(VT*)(lo_out + off) = *(VT*)low;
}

// ---------------- old fp32 aggregation (fallback path) ----------------
template <int D>
__global__ __launch_bounds__(256) void k_agg(const float* __restrict__ h, float* __restrict__ out,
                                             const int* __restrict__ rowptr,
                                             const int* __restrict__ csr_src,
                                             const float* __restrict__ csr_w,
                                             const float* __restrict__ dinv) {
    constexpr int NF2 = D / 128;
    int node = blockIdx.x * 4 + (threadIdx.x >> 6);
    int lane = threadIdx.x & 63;
    const float2* hn = (const float2*)(h + (size_t)node * D);
    float dn = dinv[node];
    float w0 = dn * dn;
    float2 acc[NF2];
#pragma unroll
    for (int j = 0; j < NF2; ++j) {
        float2 v = hn[lane + j * 64];
        acc[j].x = v.x * w0;
        acc[j].y = v.y * w0;
    }
    int beg = rowptr[node], end = rowptr[node + 1];
    for (int e = beg; e < end; ++e) {
        int s = csr_src[e];
        float w = csr_w[e];
        const float2* hs = (const float2*)(h + (size_t)s * D);
#pragma unroll
        for (int j = 0; j < NF2; ++j) {
            float2 v = hs[lane + j * 64];
            acc[j].x += v.x * w;
            acc[j].y += v.y * w;
        }
    }
    float2* op = (float2*)(out + (size_t)node * D);
#pragma unroll
    for (int j = 0; j < NF2; ++j) op[lane + j * 64] = acc[j];
}

// ---------------- small per-node linear (fallback path) ----------------
template <int OUTS>
__global__ __launch_bounds__(64) void k_linear_small(const float* __restrict__ A,
                                                     const float* __restrict__ W,
                                                     const float* __restrict__ bias,
                                                     float* __restrict__ Cf,
                                                     u16* __restrict__ Chi,
                                                     u16* __restrict__ Clo,
                                                     int K, int N, int relu) {
    int n = blockIdx.y;
    int o = blockIdx.x * 64 + threadIdx.x;
    if (o >= N) return;
    float s = bias[o];
    const float* a = A + (size_t)n * K;
    for (int k = 0; k < K; ++k) s += a[k] * W[(size_t)k * N + o];
    if (relu) s = fmaxf(s, 0.0f);
    if (OUTS == 0) {
        Cf[(size_t)n * N + o] = s;
    } else {
        u16 h = f2bf(s);
        Chi[(size_t)n * N + o] = h;
        Clo[(size_t)n * N + o] = f2bf(s - bf2f(h));
    }
}

// ---------------- barrier-free, LDS-free MFMA split-bf16 GEMM ----------------
// 128x64 tile, 4 waves in a 2x2 grid (WM=64, WN=32; FM=4, FN=2). BOTH operands
// loaded straight from L2 as per-lane 16B register loads: A in natural [M][K]
// layout (one bf16x8 load per fragment), B in fragment-linear layout. Zero
// __shared__, zero barriers, zero inline asm: waves slip freely, the compiler
// software-pipelines loads across K-steps.
template <int OUTS>
__global__ __launch_bounds__(256) void k_gemm_nolds(
    const u16* __restrict__ Ahi, const u16* __restrict__ Alo,   // [M][K]
    const u16* __restrict__ Bhi, const u16* __restrict__ Blo,   // frag-linear [K/8][N][8]
    const float* __restrict__ bias,
    float* __restrict__ Cf, u16* __restrict__ Chi, u16* __restrict__ Clo,
    int M, int N, int K, int relu) {
    constexpr int BM = 128, BN = 64, WM = 64, WN = 32;
    constexpr int FM = WM / 16, FN = WN / 16;     // 4, 2

    const int tid = threadIdx.x;
    const int lane = tid & 63;
    const int wave = tid >> 6;
    const int wy = wave >> 1, wx = wave & 1;

    // XCD-chunked bijective swizzle (all grids have nwg % 8 == 0)
    const int nwg = gridDim.x * gridDim.y;
    const int d = blockIdx.y * gridDim.x + blockIdx.x;
    const int q = nwg >> 3;
    const int lg = (d & 7) * q + (d >> 3);
    const int bx = lg % gridDim.x, by = lg / gridDim.x;
    const int m0 = by * BM, n0 = bx * BN;

    const int kc = lane >> 4, rr = lane & 15;

    // A fragment bases: row = m0 + wy*64 + fm*16 + rr ; elem = row*K + kc*8
    const u16* aph[FM];
    const u16* apl[FM];
#pragma unroll
    for (int fm = 0; fm < FM; ++fm) {
        size_t ro = (size_t)(m0 + wy * 64 + fm * 16 + rr) * K + kc * 8;
        aph[fm] = Ahi + ro;
        apl[fm] = Alo + ro;
    }
    // B fragment base (frag-linear): chunk kc, col n0 + wx*32 + fn*16 + rr
    const size_t bbase = ((size_t)kc * N + n0 + wx * WN + rr) * 8;
    const size_t bstep = (size_t)4 * N * 8; // elems per K-step (4 chunks)

    f32x4 acc[FM][FN];
#pragma unroll
    for (int i = 0; i < FM; ++i)
#pragma unroll
        for (int j = 0; j < FN; ++j) acc[i][j] = f32x4{0.f, 0.f, 0.f, 0.f};

    const int nks = K / 32; // 4..32, always a multiple of 4
#pragma unroll 4
    for (int ks = 0; ks < nks; ++ks) {
        bf16x8 ah[FM], al[FM], bh[FN], bl[FN];
#pragma unroll
        for (int fm = 0; fm < FM; ++fm) {
            ah[fm] = *(const bf16x8*)(aph[fm] + ks * 32);
            al[fm] = *(const bf16x8*)(apl[fm] + ks * 32);
        }
#pragma unroll
        for (int fn = 0; fn < FN; ++fn) {
            bh[fn] = *(const bf16x8*)(Bhi + bbase + (size_t)ks * bstep + fn * 128);
            bl[fn] = *(const bf16x8*)(Blo + bbase + (size_t)ks * bstep + fn * 128);
        }
#pragma unroll
        for (int fm = 0; fm < FM; ++fm)
#pragma unroll
            for (int fn = 0; fn < FN; ++fn) {
                acc[fm][fn] = __builtin_amdgcn_mfma_f32_16x16x32_bf16(ah[fm], bh[fn], acc[fm][fn], 0, 0, 0);
                acc[fm][fn] = __builtin_amdgcn_mfma_f32_16x16x32_bf16(al[fm], bh[fn], acc[fm][fn], 0, 0, 0);
                acc[fm][fn] = __builtin_amdgcn_mfma_f32_16x16x32_bf16(ah[fm], bl[fn], acc[fm][fn], 0, 0, 0);
            }
    }

    const int cr = (lane >> 4) * 4;
    const int cc = lane & 15;
#pragma unroll
    for (int fm = 0; fm < FM; ++fm)
#pragma unroll
        for (int fn = 0; fn < FN; ++fn) {
            int col = n0 + wx * WN + fn * 16 + cc;
            float bv = bias[col];
#pragma unroll
            for (int r = 0; r < 4; ++r) {
                int row = m0 + wy * 64 + fm * 16 + cr + r;
                float v = acc[fm][fn][r] + bv;
                if (relu) v = fmaxf(v, 0.f);
                if (OUTS == 0) {
                    Cf[(size_t)row * N + col] = v;
                } else {
                    u16 h = f2bf(v);
                    Chi[(size_t)row * N + col] = h;
                    Clo[(size_t)row * N + col] = f2bf(v - bf2f(h));
                }
            }
        }
}

// ---------------- old fp32 tiled GEMM (fallback path) ----------------
template <int BM, int BN, int BK, int TM, int TN>
__global__ __launch_bounds__(256) void k_gemm(const float* __restrict__ A,
                                              const float* __restrict__ W,
                                              const float* __restrict__ bias,
                                              float* __restrict__ C,
                                              int M, int N, int K, int relu) {
    constexpr int TX = BN / TN;
    constexpr int TY = BM / TM;
    __shared__ float As[BK][BM + 4];
    __shared__ float Bs[BK][BN];
    int tid = threadIdx.x;
    int tx = tid % TX, ty = tid / TX;
    int m0 = blockIdx.y * BM, n0 = blockIdx.x * BN;
    float acc[TM][TN] = {};
    for (int k0 = 0; k0 < K; k0 += BK) {
        for (int v = tid; v < BM * BK / 4; v += TX * TY) {
            int r = v / (BK / 4);
            int kcp = (v % (BK / 4)) * 4;
            float4 val = *(const float4*)&A[(size_t)(m0 + r) * K + k0 + kcp];
            As[kcp + 0][r] = val.x; As[kcp + 1][r] = val.y;
            As[kcp + 2][r] = val.z; As[kcp + 3][r] = val.w;
        }
        for (int v = tid; v < BK * BN / 4; v += TX * TY) {
            int kr = v / (BN / 4);
            int c = (v % (BN / 4)) * 4;
            *(float4*)&Bs[kr][c] = *(const float4*)&W[(size_t)(k0 + kr) * N + n0 + c];
        }
        __syncthreads();
#pragma unroll
        for (int kk = 0; kk < BK; ++kk) {
            float a[TM], b[TN];
#pragma unroll
            for (int i = 0; i < TM; i += 4) {
                float4 t4 = *(const float4*)&As[kk][ty * TM + i];
                a[i] = t4.x; a[i + 1] = t4.y; a[i + 2] = t4.z; a[i + 3] = t4.w;
            }
#pragma unroll
            for (int j = 0; j < TN; j += 4) {
                float4 t4 = *(const float4*)&Bs[kk][tx * TN + j];
                b[j] = t4.x; b[j + 1] = t4.y; b[j + 2] = t4.z; b[j + 3] = t4.w;
            }
#pragma unroll
            for (int i = 0; i < TM; ++i)
#pragma unroll
                for (int j = 0; j < TN; ++j) acc[i][j] += a[i] * b[j];
        }
        __syncthreads();
    }
#pragma unroll
    for (int i = 0; i < TM; ++i) {
        int row = m0 + ty * TM + i;
#pragma unroll
        for (int j = 0; j < TN; j += 4) {
            int col = n0 + tx * TN + j;
            float4 v;
            v.x = acc[i][j + 0] + bias[col + 0];
            v.y = acc[i][j + 1] + bias[col + 1];
            v.z = acc[i][j + 2] + bias[col + 2];
            v.w = acc[i][j + 3] + bias[col + 3];
            if (relu) {
                v.x = fmaxf(v.x, 0.0f); v.y = fmaxf(v.y, 0.0f);
                v.z = fmaxf(v.z, 0.0f); v.w = fmaxf(v.w, 0.0f);
            }
            *(float4*)&C[(size_t)row * N + col] = v;
        }
    }
}

// ---------------- softmax over 50 cols (fallback path) ----------------
__global__ __launch_bounds__(256) void k_softmax50(const float* __restrict__ in,
                                                   float* __restrict__ out) {
    int row = blockIdx.x * 4 + (threadIdx.x >> 6);
    int lane = threadIdx.x & 63;
    float v = (lane < 50) ? in[(size_t)row * 50 + lane] : -INFINITY;
    float m = v;
#pragma unroll
    for (int off = 32; off; off >>= 1) m = fmaxf(m, __shfl_xor(m, off));
    float e = (lane < 50) ? expf(v - m) : 0.0f;
    float s = e;
#pragma unroll
    for (int off = 32; off; off >>= 1) s += __shfl_xor(s, off);
    if (lane < 50) out[(size_t)row * 50 + lane] = e / s;
}

// ---------------- launch ----------------

extern "C" void kernel_launch(void* const* d_in, const int* in_sizes, int n_in,
                              void* d_out, int out_size, void* d_ws, size_t ws_size,
                              hipStream_t stream) {
    const float* x  = (const float*)d_in[0];
    const int*   ei = (const int*)d_in[1];
    const float *w1  = (const float*)d_in[2],  *b1  = (const float*)d_in[3];
    const float *w2  = (const float*)d_in[4],  *b2  = (const float*)d_in[5];
    const float *w3  = (const float*)d_in[6],  *b3  = (const float*)d_in[7];
    const float *g1w = (const float*)d_in[8],  *g1b = (const float*)d_in[9];
    const float *g2w = (const float*)d_in[10], *g2b = (const float*)d_in[11];
    const float *g3w = (const float*)d_in[12], *g3b = (const float*)d_in[13];
    const float *d1w = (const float*)d_in[14], *d1b = (const float*)d_in[15];
    const float *d2w = (const float*)d_in[16], *d2b = (const float*)d_in[17];
    const float *d3w = (const float*)d_in[18], *d3b = (const float*)d_in[19];
    const float *d4w = (const float*)d_in[20], *d4b = (const float*)d_in[21];
    float* out = (float*)d_out;

    const size_t NEED_NEW = 57016576ull;

    if (ws_size >= NEED_NEW) {
        // ---- split-bf16 MFMA path ----
        char* w = (char*)d_ws;
        u16* p0hi = (u16*)w;                        // 8192x1024
        u16* p0lo = (u16*)(w + 16777216);
        u16* p1hi = (u16*)(w + 33554432);           // 8192x512
        u16* p1lo = (u16*)(w + 41943040);
        float* f0 = (float*)p1hi;  // fp32 scratch overlays P1
        u16* wts = (u16*)(w + 50331648);
        u16 *wt1h = wts,            *wt1l = wt1h + 32768;
        u16 *wt2h = wt1l + 32768,   *wt2l = wt2h + 131072;
        u16 *wt3h = wt2l + 131072,  *wt3l = wt3h + 524288;
        u16 *wd1h = wt3l + 524288,  *wd1l = wd1h + 524288;
        u16 *wd2h = wd1l + 524288,  *wd2l = wd2h + 131072;
        u16 *wd3h = wd2l + 131072,  *wd3l = wd3h + 32768;
        char* cs = w + 55836672;
        int*   deg     = (int*)cs;
        int*   rowptr  = deg + N_NODES;
        int*   pos     = rowptr + 8256;
        float* dinv    = (float*)(pos + N_NODES);
        int*   csr_src = (int*)(dinv + N_NODES);
        float* csr_w   = (float*)(csr_src + N_EDGES);

        // merged weight prep + deg zeroing (must precede k_count)
        k_prep_all<<<1376256 / 256, 256, 0, stream>>>(g1w, g2w, g3w, d1w, d2w, d3w, wts, deg);

        // CSR build
        k_count<<<N_EDGES / 256, 256, 0, stream>>>(ei, deg);
        k_scan<<<1, 1024, 0, stream>>>(deg, rowptr, pos, dinv);
        k_fill<<<N_EDGES / 256, 256, 0, stream>>>(ei, dinv, pos, csr_src, csr_w);

        // fused encoder
        k_enc_fused<<<N_NODES / 4, 256, 0, stream>>>(x, w1, b1, w2, b2, w3, b3, p0hi, p0lo);

        // gcn1: agg(128) then 128->256
        k_agg_s<128><<<N_NODES / 4, 256, 0, stream>>>(p0hi, p0lo, p1hi, p1lo, rowptr, csr_src, csr_w, dinv);
        k_gemm_nolds<1><<<dim3(256 / 64, N_NODES / 128), 256, 0, stream>>>(
            p1hi, p1lo, wt1h, wt1l, g1b, nullptr, p0hi, p0lo, N_NODES, 256, 128, 1);
        // gcn2: agg(256) then 256->512
        k_agg_s<256><<<N_NODES / 4, 256, 0, stream>>>(p0hi, p0lo, p1hi, p1lo, rowptr, csr_src, csr_w, dinv);
        k_gemm_nolds<1><<<dim3(512 / 64, N_NODES / 128), 256, 0, stream>>>(
            p1hi, p1lo, wt2h, wt2l, g2b, nullptr, p0hi, p0lo, N_NODES, 512, 256, 1);
        // gcn3: agg(512) then 512->1024
        k_agg_s<512><<<N_NODES / 4, 256, 0, stream>>>(p0hi, p0lo, p1hi, p1lo, rowptr, csr_src, csr_w, dinv);
        k_gemm_nolds<1><<<dim3(1024 / 64, N_NODES / 128), 256, 0, stream>>>(
            p1hi, p1lo, wt3h, wt3l, g3b, nullptr, p0hi, p0lo, N_NODES, 1024, 512, 1);
        // decoder
        k_gemm_nolds<1><<<dim3(512 / 64, N_NODES / 128), 256, 0, stream>>>(
            p0hi, p0lo, wd1h, wd1l, d1b, nullptr, p1hi, p1lo, N_NODES, 512, 1024, 1);
        k_gemm_nolds<1><<<dim3(256 / 64, N_NODES / 128), 256, 0, stream>>>(
            p1hi, p1lo, wd2h, wd2l, d2b, nullptr, p0hi, p0lo, N_NODES, 256, 512, 1);
        k_gemm_nolds<0><<<dim3(128 / 64, N_NODES / 128), 256, 0, stream>>>(
            p0hi, p0lo, wd3h, wd3l, d3b, f0, nullptr, nullptr, N_NODES, 128, 256, 1);

        // fused d4 + softmax
        k_d4sm_fused<<<N_NODES / 4, 256, 0, stream>>>(f0, d4w, d4b, out);
    } else {
        // ---- fallback: fp32 path ----
        float* bufA = (float*)d_ws;
        float* bufB = bufA + (size_t)N_NODES * 1024;
        int*   deg     = (int*)(bufB + (size_t)N_NODES * 512);
        int*   rowptr  = deg + N_NODES;
        int*   pos     = rowptr + 8256;
        float* dinv    = (float*)(pos + N_NODES);
        int*   csr_src = (int*)(dinv + N_NODES);
        float* csr_w   = (float*)(csr_src + N_EDGES);

        hipMemsetAsync(deg, 0, N_NODES * sizeof(int), stream);
        k_count<<<N_EDGES / 256, 256, 0, stream>>>(ei, deg);
        k_scan<<<1, 1024, 0, stream>>>(deg, rowptr, pos, dinv);
        k_fill<<<N_EDGES / 256, 256, 0, stream>>>(ei, dinv, pos, csr_src, csr_w);

        k_linear_small<0><<<dim3(1, N_NODES), 64, 0, stream>>>(x,    w1, b1, bufA, nullptr, nullptr, 3, 32, 1);
        k_linear_small<0><<<dim3(1, N_NODES), 64, 0, stream>>>(bufA, w2, b2, bufB, nullptr, nullptr, 32, 64, 1);
        k_linear_small<0><<<dim3(2, N_NODES), 64, 0, stream>>>(bufB, w3, b3, bufA, nullptr, nullptr, 64, 128, 1);

        k_agg<128><<<N_NODES / 4, 256, 0, stream>>>(bufA, bufB, rowptr, csr_src, csr_w, dinv);
        k_gemm<64, 64, 16, 4, 4><<<dim3(256 / 64, N_NODES / 64), 256, 0, stream>>>(
            bufB, g1w, g1b, bufA, N_NODES, 256, 128, 1);
        k_agg<256><<<N_NODES / 4, 256, 0, stream>>>(bufA, bufB, rowptr, csr_src, csr_w, dinv);
        k_gemm<128, 128, 16, 8, 8><<<dim3(512 / 128, N_NODES / 128), 256, 0, stream>>>(
            bufB, g2w, g2b, bufA, N_NODES, 512, 256, 1);
        k_agg<512><<<N_NODES / 4, 256, 0, stream>>>(bufA, bufB, rowptr, csr_src, csr_w, dinv);
        k_gemm<128, 128, 16, 8, 8><<<dim3(1024 / 128, N_NODES / 128), 256, 0, stream>>>(
            bufB, g3w, g3b, bufA, N_NODES, 1024, 512, 1);
        k_gemm<128, 128, 16, 8, 8><<<dim3(512 / 128, N_NODES / 128), 256, 0, stream>>>(
            bufA, d1w, d1b, bufB, N_NODES, 512, 1024, 1);
        k_gemm<64, 64, 16, 4, 4><<<dim3(256 / 64, N_NODES / 64), 256, 0, stream>>>(
            bufB, d2w, d2b, bufA, N_NODES, 256, 512, 1);
        k_gemm<64, 64, 16, 4, 4><<<dim3(128 / 64, N_NODES / 64), 256, 0, stream>>>(
            bufA, d3w, d3b, bufB, N_NODES, 128, 256, 1);
        k_linear_small<0><<<dim3(1, N_NODES), 64, 0, stream>>>(bufB, d4w, d4b, bufA, nullptr, nullptr, 128, 50, 0);
        k_softmax50<<<N_NODES / 4, 256, 0, stream>>>(bufA, out);
    }
}

// Round 20
// 280.225 us; speedup vs baseline: 1.4063x; 1.4063x over previous
//
#include <hip/hip_runtime.h>
#include <math.h>

#define N_NODES 8192
#define N_EDGES 131072

typedef unsigned short u16;
typedef unsigned int u32;
typedef short bf16x8 __attribute__((ext_vector_type(8)));
typedef int v4i __attribute__((ext_vector_type(4)));
typedef float f32x4 __attribute__((ext_vector_type(4)));

__device__ __forceinline__ u16 f2bf(float x) {
    unsigned u = __float_as_uint(x);
    u += 0x7fffu + ((u >> 16) & 1u);
    return (u16)(u >> 16);
}
__device__ __forceinline__ float bf2f(u16 h) { return __uint_as_float(((unsigned)h) << 16); }

#define GLD_LDS(gp, lp) __builtin_amdgcn_global_load_lds( \
    (const __attribute__((address_space(1))) void*)(gp),  \
    (__attribute__((address_space(3))) void*)(lp), 16, 0, 0)

template <int N> __device__ __forceinline__ void wait_vmcnt() {
    if constexpr (N == 0) asm volatile("s_waitcnt vmcnt(0)" ::: "memory");
    else if constexpr (N == 4) asm volatile("s_waitcnt vmcnt(4)" ::: "memory");
    else static_assert(N < 0, "unsupported vmcnt");
}

// raw LDS byte offset of a __shared__ object
__device__ __forceinline__ u32 lds_addr(const void* p) {
    return (u32)(size_t)(const __attribute__((address_space(3))) void*)p;
}

// inline-asm ds_read_b128 (invisible to compiler LDS-DMA waitcnt pass).
__device__ __forceinline__ bf16x8 lds_read_b128(u32 addr) {
    v4i r;
    asm volatile("ds_read_b128 %0, %1" : "=v"(r) : "v"(addr));
    union { v4i i; bf16x8 b; } u;
    u.i = r;
    return u.b;
}

template <int NU> struct UV;
template <> struct UV<1> { typedef u32 T; };
template <> struct UV<2> { typedef uint2 T; };
template <> struct UV<4> { typedef uint4 T; };

// ---------------- degree / CSR build ----------------

__global__ void k_count(const int* __restrict__ ei, int* __restrict__ deg) {
    int e = blockIdx.x * 256 + threadIdx.x;
    if (e < N_EDGES) atomicAdd(&deg[ei[N_EDGES + e]], 1);
}

__global__ __launch_bounds__(1024) void k_scan(const int* __restrict__ deg,
                                               int* __restrict__ rowptr,
                                               int* __restrict__ pos,
                                               float* __restrict__ dinv) {
    __shared__ int sums[1024];
    int t = threadIdx.x;
    int local[8];
    int s = 0;
#pragma unroll
    for (int i = 0; i < 8; ++i) {
        local[i] = deg[t * 8 + i];
        dinv[t * 8 + i] = 1.0f / sqrtf((float)(local[i] + 1));
        s += local[i];
    }
    sums[t] = s;
    __syncthreads();
    for (int off = 1; off < 1024; off <<= 1) {
        int v = (t >= off) ? sums[t - off] : 0;
        __syncthreads();
        sums[t] += v;
        __syncthreads();
    }
    int run = sums[t] - s;
#pragma unroll
    for (int i = 0; i < 8; ++i) {
        rowptr[t * 8 + i] = run;
        pos[t * 8 + i] = run;
        run += local[i];
    }
    if (t == 1023) rowptr[8192] = run;
}

__global__ void k_fill(const int* __restrict__ ei, const float* __restrict__ dinv,
                       int* __restrict__ pos, int* __restrict__ csr_src,
                       float* __restrict__ csr_w) {
    int e = blockIdx.x * 256 + threadIdx.x;
    if (e < N_EDGES) {
        int s = ei[e];
        int t = ei[N_EDGES + e];
        int idx = atomicAdd(&pos[t], 1);
        csr_src[idx] = s;
        csr_w[idx] = dinv[s] * dinv[t];
    }
}

// ---------------- merged weight prep (+ deg zeroing folded in) ----------------
// fragment-linear global layout per plane: elem B[n][k] stored at
// ((k>>3)*N + n)*8 + (k&7)
__global__ void k_prep_all(const float* __restrict__ g1w, const float* __restrict__ g2w,
                           const float* __restrict__ g3w, const float* __restrict__ d1w,
                           const float* __restrict__ d2w, const float* __restrict__ d3w,
                           u16* __restrict__ wts, int* __restrict__ deg) {
    int idx = blockIdx.x * 256 + threadIdx.x; // < 1376256
    if (idx < N_NODES) deg[idx] = 0;          // folded k_zero_deg (runs before k_count)
    const float* W;
    int local, lgK, N;
    u16 *hi, *lo;
    if (idx < 32768)        { W = g1w; local = idx;           lgK = 7;  N = 256;  hi = wts;           lo = wts + 32768; }
    else if (idx < 163840)  { W = g2w; local = idx - 32768;   lgK = 8;  N = 512;  hi = wts + 65536;   lo = wts + 196608; }
    else if (idx < 688128)  { W = g3w; local = idx - 163840;  lgK = 9;  N = 1024; hi = wts + 327680;  lo = wts + 851968; }
    else if (idx < 1212416) { W = d1w; local = idx - 688128;  lgK = 10; N = 512;  hi = wts + 1376256; lo = wts + 1900544; }
    else if (idx < 1343488) { W = d2w; local = idx - 1212416; lgK = 9;  N = 256;  hi = wts + 2424832; lo = wts + 2555904; }
    else if (idx < 1376256) { W = d3w; local = idx - 1343488; lgK = 8;  N = 128;  hi = wts + 2686976; lo = wts + 2719744; }
    else return;
    int n = local >> lgK;
    int k = local & ((1 << lgK) - 1);
    float v = W[(size_t)k * N + n];
    u16 h = f2bf(v);
    int dst = ((k >> 3) * N + n) * 8 + (k & 7);
    hi[dst] = h;
    lo[dst] = f2bf(v - bf2f(h));
}

// ---------------- fused encoder ----------------
__global__ __launch_bounds__(256) void k_enc_fused(const float* __restrict__ x,
                                                   const float* __restrict__ w1, const float* __restrict__ b1,
                                                   const float* __restrict__ w2, const float* __restrict__ b2,
                                                   const float* __restrict__ w3, const float* __restrict__ b3,
                                                   u16* __restrict__ Chi, u16* __restrict__ Clo) {
    __shared__ float lw[10560];
    const int tid = threadIdx.x;
    for (int i = tid; i < 96; i += 256) lw[i] = w1[i];
    for (int i = tid; i < 32; i += 256) lw[96 + i] = b1[i];
    for (int i = tid; i < 2048; i += 256) lw[128 + i] = w2[i];
    for (int i = tid; i < 64; i += 256) lw[2176 + i] = b2[i];
    for (int i = tid; i < 8192; i += 256) lw[2240 + i] = w3[i];
    for (int i = tid; i < 128; i += 256) lw[10432 + i] = b3[i];
    __syncthreads();

    const int lane = tid & 63;
    const int node = blockIdx.x * 4 + (tid >> 6);

    float x0 = x[node * 3 + 0], x1 = x[node * 3 + 1], x2 = x[node * 3 + 2];

    int o1 = lane & 31;
    float h1 = fmaxf(x0 * lw[o1] + x1 * lw[32 + o1] + x2 * lw[64 + o1] + lw[96 + o1], 0.f);

    float h2 = lw[2176 + lane];
#pragma unroll
    for (int k = 0; k < 32; ++k) h2 += __shfl(h1, k) * lw[128 + k * 64 + lane];
    h2 = fmaxf(h2, 0.f);

    float h3a = lw[10432 + lane];
    float h3b = lw[10432 + 64 + lane];
#pragma unroll
    for (int k = 0; k < 64; ++k) {
        float hk = __shfl(h2, k);
        h3a += hk * lw[2240 + k * 128 + lane];
        h3b += hk * lw[2240 + k * 128 + 64 + lane];
    }
    h3a = fmaxf(h3a, 0.f);
    h3b = fmaxf(h3b, 0.f);

    size_t base = (size_t)node * 128;
    u16 ha = f2bf(h3a), hb = f2bf(h3b);
    Chi[base + lane] = ha;
    Chi[base + 64 + lane] = hb;
    Clo[base + lane] = f2bf(h3a - bf2f(ha));
    Clo[base + 64 + lane] = f2bf(h3b - bf2f(hb));
}

// ---------------- fused d4 (128 -> 50) + softmax ----------------
__global__ __launch_bounds__(256) void k_d4sm_fused(const float* __restrict__ A,
                                                    const float* __restrict__ W,
                                                    const float* __restrict__ bias,
                                                    float* __restrict__ out) {
    __shared__ float lw[6450];
    const int tid = threadIdx.x;
    for (int i = tid; i < 6400; i += 256) lw[i] = W[i];
    for (int i = tid; i < 50; i += 256) lw[6400 + i] = bias[i];
    __syncthreads();

    const int lane = tid & 63;
    const int node = blockIdx.x * 4 + (tid >> 6);

    float a0 = A[(size_t)node * 128 + lane];
    float a1 = A[(size_t)node * 128 + 64 + lane];

    float acc = (lane < 50) ? lw[6400 + lane] : 0.f;
    int oc = (lane < 50) ? lane : 0;
#pragma unroll
    for (int k = 0; k < 64; ++k) acc += __shfl(a0, k) * lw[k * 50 + oc];
#pragma unroll
    for (int k = 0; k < 64; ++k) acc += __shfl(a1, k) * lw[(64 + k) * 50 + oc];

    float v = (lane < 50) ? acc : -INFINITY;
    float m = v;
#pragma unroll
    for (int off = 32; off; off >>= 1) m = fmaxf(m, __shfl_xor(m, off));
    float e = (lane < 50) ? expf(v - m) : 0.f;
    float s = e;
#pragma unroll
    for (int off = 32; off; off >>= 1) s += __shfl_xor(s, off);
    if (lane < 50) out[(size_t)node * 50 + lane] = e / s;
}

// ---------------- aggregation on split bf16 planes ----------------
template <int D>
__global__ __launch_bounds__(256) void k_agg_s(const u16* __restrict__ hi_in,
                                               const u16* __restrict__ lo_in,
                                               u16* __restrict__ hi_out,
                                               u16* __restrict__ lo_out,
                                               const int* __restrict__ rowptr,
                                               const int* __restrict__ csr_src,
                                               const float* __restrict__ csr_w,
                                               const float* __restrict__ dinv) {
    constexpr int EPL = D / 64;
    constexpr int NU = EPL / 2;
    using VT = typename UV<NU>::T;
    int node = blockIdx.x * 4 + (threadIdx.x >> 6);
    int lane = threadIdx.x & 63;
    const size_t off = (size_t)node * D + lane * EPL;
    float acc[EPL];
    {
        float dn = dinv[node];
        float w0 = dn * dn;
        u32 hu[NU], lu[NU];
        *(VT*)hu = *(const VT*)(hi_in + off);
        *(VT*)lu = *(const VT*)(lo_in + off);
#pragma unroll
        for (int j = 0; j < NU; ++j) {
            acc[2 * j]     = (__uint_as_float(hu[j] << 16) + __uint_as_float(lu[j] << 16)) * w0;
            acc[2 * j + 1] = (__uint_as_float(hu[j] & 0xffff0000u) + __uint_as_float(lu[j] & 0xffff0000u)) * w0;
        }
    }
#define EDGE_ACC(S, W) do {                                                            \
        size_t so = (size_t)(S) * D + lane * EPL;                                      \
        u32 hu[NU], lu[NU];                                                            \
        *(VT*)hu = *(const VT*)(hi_in + so);                                           \
        *(VT*)lu = *(const VT*)(lo_in + so);                                           \
        _Pragma("unroll")                                                              \
        for (int j = 0; j < NU; ++j) {                                                 \
            acc[2 * j]     += (__uint_as_float(hu[j] << 16) + __uint_as_float(lu[j] << 16)) * (W); \
            acc[2 * j + 1] += (__uint_as_float(hu[j] & 0xffff0000u) + __uint_as_float(lu[j] & 0xffff0000u)) * (W); \
        }                                                                              \
    } while (0)
    int beg = rowptr[node], end = rowptr[node + 1];
    int e = beg;
    for (; e + 2 <= end; e += 2) {
        int s0 = csr_src[e], s1 = csr_src[e + 1];
        float wa = csr_w[e], wb = csr_w[e + 1];
        EDGE_ACC(s0, wa);
        EDGE_ACC(s1, wb);
    }
    if (e < end) EDGE_ACC(csr_src[e], csr_w[e]);
#undef EDGE_ACC
    u32 how[NU], low[NU];
#pragma unroll
    for (int j = 0; j < NU; ++j) {
        u16 h0 = f2bf(acc[2 * j]);     u16 l0 = f2bf(acc[2 * j] - bf2f(h0));
        u16 h1 = f2bf(acc[2 * j + 1]); u16 l1 = f2bf(acc[2 * j + 1] - bf2f(h1));
        how[j] = (u32)h0 | ((u32)h1 << 16);
        low[j] = (u32)l0 | ((u32)l1 << 16);
    }
    *(VT*)(hi_out + off) = *(VT*)how;
    *(VT*)(lo_out + off) = *(VT*)low;
}

// ---------------- old fp32 aggregation (fallback path) ----------------
template <int D>
__global__ __launch_bounds__(256) void k_agg(const float* __restrict__ h, float* __restrict__ out,
                                             const int* __restrict__ rowptr,
                                             const int* __restrict__ csr_src,
                                             const float* __restrict__ csr_w,
                                             const float* __restrict__ dinv) {
    constexpr int NF2 = D / 128;
    int node = blockIdx.x * 4 + (threadIdx.x >> 6);
    int lane = threadIdx.x & 63;
    const float2* hn = (const float2*)(h + (size_t)node * D);
    float dn = dinv[node];
    float w0 = dn * dn;
    float2 acc[NF2];
#pragma unroll
    for (int j = 0; j < NF2; ++j) {
        float2 v = hn[lane + j * 64];
        acc[j].x = v.x * w0;
        acc[j].y = v.y * w0;
    }
    int beg = rowptr[node], end = rowptr[node + 1];
    for (int e = beg; e < end; ++e) {
        int s = csr_src[e];
        float w = csr_w[e];
        const float2* hs = (const float2*)(h + (size_t)s * D);
#pragma unroll
        for (int j = 0; j < NF2; ++j) {
            float2 v = hs[lane + j * 64];
            acc[j].x += v.x * w;
            acc[j].y += v.y * w;
        }
    }
    float2* op = (float2*)(out + (size_t)node * D);
#pragma unroll
    for (int j = 0; j < NF2; ++j) op[lane + j * 64] = acc[j];
}

// ---------------- small per-node linear (fallback path) ----------------
template <int OUTS>
__global__ __launch_bounds__(64) void k_linear_small(const float* __restrict__ A,
                                                     const float* __restrict__ W,
                                                     const float* __restrict__ bias,
                                                     float* __restrict__ Cf,
                                                     u16* __restrict__ Chi,
                                                     u16* __restrict__ Clo,
                                                     int K, int N, int relu) {
    int n = blockIdx.y;
    int o = blockIdx.x * 64 + threadIdx.x;
    if (o >= N) return;
    float s = bias[o];
    const float* a = A + (size_t)n * K;
    for (int k = 0; k < K; ++k) s += a[k] * W[(size_t)k * N + o];
    if (relu) s = fmaxf(s, 0.0f);
    if (OUTS == 0) {
        Cf[(size_t)n * N + o] = s;
    } else {
        u16 h = f2bf(s);
        Chi[(size_t)n * N + o] = h;
        Clo[(size_t)n * N + o] = f2bf(s - bf2f(h));
    }
}

// ---------------- MFMA split-bf16 GEMM (best measured: 280.6us config) --------
// 128x128 tile, WM=128/WN=32 (FM=8, FN=2): each wave owns a distinct 32-col
// strip -> every B fragment loaded exactly once per block. A staged via
// global_load_lds (2x16KB buffers); B direct from L2 (fragment-linear),
// register double-buffered one K-step ahead. launch_bounds(256,2), no spill.
template <int OUTS>
__global__ __launch_bounds__(256, 2) void k_gemm_mfma(
    const u16* __restrict__ Ahi, const u16* __restrict__ Alo,
    const u16* __restrict__ Bhi, const u16* __restrict__ Blo, // fragment-linear [K/8][N][8]
    const float* __restrict__ bias,
    float* __restrict__ Cf, u16* __restrict__ Chi, u16* __restrict__ Clo,
    int M, int N, int K, int relu) {
    constexpr int BM = 128, BN = 128, WN = 32;
    constexpr int BK = 32;
    constexpr int FM = BM / 16, FN = WN / 16;     // 8, 2
    constexpr int ASZ = (BK / 8) * BM * 16;       // 8192 B per A plane
    constexpr int TOT = 2 * ASZ;                  // 16384 B (A only)
    constexpr int NSTG = TOT / 4096;              // 4 gld_lds per thread

    __shared__ char lds0[TOT] __attribute__((aligned(16)));
    __shared__ char lds1[TOT] __attribute__((aligned(16)));

    const int tid = threadIdx.x;
    const int lane = tid & 63;
    const int wave = tid >> 6;   // column strip owner

    // XCD-chunked bijective swizzle (all grids have nwg % 8 == 0)
    const int nwg = gridDim.x * gridDim.y;
    const int d = blockIdx.y * gridDim.x + blockIdx.x;
    const int q = nwg >> 3;
    const int lg = (d & 7) * q + (d >> 3);
    const int bx = lg % gridDim.x, by = lg / gridDim.x;
    const int m0 = by * BM, n0 = bx * BN;

    // A staging decode (K-step invariant)
    const u16* gp[NSTG];
    int ldo[NSTG];
#pragma unroll
    for (int i = 0; i < NSTG; ++i) {
        int o = i * 4096 + tid * 16;
        ldo[i] = o;
        const u16* base;
        int roff;
        if (o < ASZ) { base = Ahi; roff = o; }
        else         { base = Alo; roff = o - ASZ; }
        int c = roff / (BM * 16);
        int r = (roff % (BM * 16)) / 16;
        gp[i] = base + (size_t)(m0 + r) * K + c * 8;
    }

    const int kc = lane >> 4, rr = lane & 15;
    const int aoff = (kc * BM + rr) * 16; // + fm*256 per fragment

    // B fragment-linear base (elems): chunk kc, row n0 + wave*WN + rr
    const size_t bbase = ((size_t)kc * N + n0 + wave * WN + rr) * 8;
    const size_t bstep = (size_t)4 * N * 8; // elems per K-step

    f32x4 acc[FM][FN];
#pragma unroll
    for (int i = 0; i < FM; ++i)
#pragma unroll
        for (int j = 0; j < FN; ++j) acc[i][j] = f32x4{0.f, 0.f, 0.f, 0.f};

    bf16x8 b0h[FN], b0l[FN], b1h[FN], b1l[FN];

#define STAGE(P, KS) do {                                          \
        _Pragma("unroll")                                          \
        for (int i = 0; i < NSTG; ++i)                             \
            GLD_LDS(gp[i] + (KS) * BK, (P) + ldo[i]);              \
    } while (0)

#define LOADB(BH, BL, KS) do {                                                      \
        _Pragma("unroll")                                                           \
        for (int fn = 0; fn < FN; ++fn) {                                           \
            BH[fn] = *(const bf16x8*)(Bhi + bbase + (size_t)(KS) * bstep + fn * 128); \
            BL[fn] = *(const bf16x8*)(Blo + bbase + (size_t)(KS) * bstep + fn * 128); \
        }                                                                           \
    } while (0)

// STEP ks: issue B(ks+1) prefetch (4 reg loads), counted wait vmcnt(4)
// (drains A(ks) DMA + B(ks); leaves the 4 new B loads in flight), barrier,
// stage A(ks+1) post-barrier (WAR-safe), asm ds_read A(ks), lgkmcnt fence,
// MFMA under setprio.
#define STEP(CUR, DST, BHC, BLC, BHD, BLD, KS) do {                                 \
        if ((KS) + 1 < nks) LOADB(BHD, BLD, (KS) + 1);                              \
        __builtin_amdgcn_sched_barrier(0);                                          \
        if ((KS) + 1 < nks) wait_vmcnt<4>(); else wait_vmcnt<0>();                  \
        asm volatile("s_barrier" ::: "memory");                                     \
        if ((KS) + 1 < nks) STAGE(DST, (KS) + 1);                                   \
        const u32 pb_ = lds_addr(CUR);                                              \
        bf16x8 ah[FM], al[FM];                                                      \
        _Pragma("unroll")                                                           \
        for (int fm = 0; fm < FM; ++fm) {                                           \
            ah[fm] = lds_read_b128(pb_ + aoff + fm * 256);                          \
            al[fm] = lds_read_b128(pb_ + ASZ + aoff + fm * 256);                    \
        }                                                                           \
        asm volatile("s_waitcnt lgkmcnt(0)");                                       \
        __builtin_amdgcn_sched_barrier(0);                                          \
        __builtin_amdgcn_s_setprio(1);                                              \
        _Pragma("unroll")                                                           \
        for (int fm = 0; fm < FM; ++fm)                                             \
            _Pragma("unroll")                                                       \
            for (int fn = 0; fn < FN; ++fn) {                                       \
                acc[fm][fn] = __builtin_amdgcn_mfma_f32_16x16x32_bf16(ah[fm], BHC[fn], acc[fm][fn], 0, 0, 0); \
                acc[fm][fn] = __builtin_amdgcn_mfma_f32_16x16x32_bf16(al[fm], BHC[fn], acc[fm][fn], 0, 0, 0); \
                acc[fm][fn] = __builtin_amdgcn_mfma_f32_16x16x32_bf16(ah[fm], BLC[fn], acc[fm][fn], 0, 0, 0); \
            }                                                                       \
        __builtin_amdgcn_s_setprio(0);                                              \
    } while (0)

    const int nks = K / BK; // 4..32, always even
    LOADB(b0h, b0l, 0);
    STAGE(lds0, 0);
    for (int base = 0; base < nks; base += 2) {
        STEP(lds0, lds1, b0h, b0l, b1h, b1l, base);
        STEP(lds1, lds0, b1h, b1l, b0h, b0l, base + 1);
    }
    asm volatile("" ::: "memory"); // DSE guard for LDS stores
#undef STEP
#undef LOADB
#undef STAGE

    const int cr = (lane >> 4) * 4;
    const int cc = lane & 15;
#pragma unroll
    for (int fm = 0; fm < FM; ++fm)
#pragma unroll
        for (int fn = 0; fn < FN; ++fn) {
            int col = n0 + wave * WN + fn * 16 + cc;
            float bv = bias[col];
#pragma unroll
            for (int r = 0; r < 4; ++r) {
                int row = m0 + fm * 16 + cr + r;
                float v = acc[fm][fn][r] + bv;
                if (relu) v = fmaxf(v, 0.f);
                if (OUTS == 0) {
                    Cf[(size_t)row * N + col] = v;
                } else {
                    u16 h = f2bf(v);
                    Chi[(size_t)row * N + col] = h;
                    Clo[(size_t)row * N + col] = f2bf(v - bf2f(h));
                }
            }
        }
}

// ---------------- old fp32 tiled GEMM (fallback path) ----------------
template <int BM, int BN, int BK, int TM, int TN>
__global__ __launch_bounds__(256) void k_gemm(const float* __restrict__ A,
                                              const float* __restrict__ W,
                                              const float* __restrict__ bias,
                                              float* __restrict__ C,
                                              int M, int N, int K, int relu) {
    constexpr int TX = BN / TN;
    constexpr int TY = BM / TM;
    __shared__ float As[BK][BM + 4];
    __shared__ float Bs[BK][BN];
    int tid = threadIdx.x;
    int tx = tid % TX, ty = tid / TX;
    int m0 = blockIdx.y * BM, n0 = blockIdx.x * BN;
    float acc[TM][TN] = {};
    for (int k0 = 0; k0 < K; k0 += BK) {
        for (int v = tid; v < BM * BK / 4; v += TX * TY) {
            int r = v / (BK / 4);
            int kcp = (v % (BK / 4)) * 4;
            float4 val = *(const float4*)&A[(size_t)(m0 + r) * K + k0 + kcp];
            As[kcp + 0][r] = val.x; As[kcp + 1][r] = val.y;
            As[kcp + 2][r] = val.z; As[kcp + 3][r] = val.w;
        }
        for (int v = tid; v < BK * BN / 4; v += TX * TY) {
            int kr = v / (BN / 4);
            int c = (v % (BN / 4)) * 4;
            *(float4*)&Bs[kr][c] = *(const float4*)&W[(size_t)(k0 + kr) * N + n0 + c];
        }
        __syncthreads();
#pragma unroll
        for (int kk = 0; kk < BK; ++kk) {
            float a[TM], b[TN];
#pragma unroll
            for (int i = 0; i < TM; i += 4) {
                float4 t4 = *(const float4*)&As[kk][ty * TM + i];
                a[i] = t4.x; a[i + 1] = t4.y; a[i + 2] = t4.z; a[i + 3] = t4.w;
            }
#pragma unroll
            for (int j = 0; j < TN; j += 4) {
                float4 t4 = *(const float4*)&Bs[kk][tx * TN + j];
                b[j] = t4.x; b[j + 1] = t4.y; b[j + 2] = t4.z; b[j + 3] = t4.w;
            }
#pragma unroll
            for (int i = 0; i < TM; ++i)
#pragma unroll
                for (int j = 0; j < TN; ++j) acc[i][j] += a[i] * b[j];
        }
        __syncthreads();
    }
#pragma unroll
    for (int i = 0; i < TM; ++i) {
        int row = m0 + ty * TM + i;
#pragma unroll
        for (int j = 0; j < TN; j += 4) {
            int col = n0 + tx * TN + j;
            float4 v;
            v.x = acc[i][j + 0] + bias[col + 0];
            v.y = acc[i][j + 1] + bias[col + 1];
            v.z = acc[i][j + 2] + bias[col + 2];
            v.w = acc[i][j + 3] + bias[col + 3];
            if (relu) {
                v.x = fmaxf(v.x, 0.0f); v.y = fmaxf(v.y, 0.0f);
                v.z = fmaxf(v.z, 0.0f); v.w = fmaxf(v.w, 0.0f);
            }
            *(float4*)&C[(size_t)row * N + col] = v;
        }
    }
}

// ---------------- softmax over 50 cols (fallback path) ----------------
__global__ __launch_bounds__(256) void k_softmax50(const float* __restrict__ in,
                                                   float* __restrict__ out) {
    int row = blockIdx.x * 4 + (threadIdx.x >> 6);
    int lane = threadIdx.x & 63;
    float v = (lane < 50) ? in[(size_t)row * 50 + lane] : -INFINITY;
    float m = v;
#pragma unroll
    for (int off = 32; off; off >>= 1) m = fmaxf(m, __shfl_xor(m, off));
    float e = (lane < 50) ? expf(v - m) : 0.0f;
    float s = e;
#pragma unroll
    for (int off = 32; off; off >>= 1) s += __shfl_xor(s, off);
    if (lane < 50) out[(size_t)row * 50 + lane] = e / s;
}

// ---------------- launch ----------------

extern "C" void kernel_launch(void* const* d_in, const int* in_sizes, int n_in,
                              void* d_out, int out_size, void* d_ws, size_t ws_size,
                              hipStream_t stream) {
    const float* x  = (const float*)d_in[0];
    const int*   ei = (const int*)d_in[1];
    const float *w1  = (const float*)d_in[2],  *b1  = (const float*)d_in[3];
    const float *w2  = (const float*)d_in[4],  *b2  = (const float*)d_in[5];
    const float *w3  = (const float*)d_in[6],  *b3  = (const float*)d_in[7];
    const float *g1w = (const float*)d_in[8],  *g1b = (const float*)d_in[9];
    const float *g2w = (const float*)d_in[10], *g2b = (const float*)d_in[11];
    const float *g3w = (const float*)d_in[12], *g3b = (const float*)d_in[13];
    const float *d1w = (const float*)d_in[14], *d1b = (const float*)d_in[15];
    const float *d2w = (const float*)d_in[16], *d2b = (const float*)d_in[17];
    const float *d3w = (const float*)d_in[18], *d3b = (const float*)d_in[19];
    const float *d4w = (const float*)d_in[20], *d4b = (const float*)d_in[21];
    float* out = (float*)d_out;

    const size_t NEED_NEW = 57016576ull;

    if (ws_size >= NEED_NEW) {
        // ---- split-bf16 MFMA path ----
        char* w = (char*)d_ws;
        u16* p0hi = (u16*)w;                        // 8192x1024
        u16* p0lo = (u16*)(w + 16777216);
        u16* p1hi = (u16*)(w + 33554432);           // 8192x512
        u16* p1lo = (u16*)(w + 41943040);
        float* f0 = (float*)p1hi;  // fp32 scratch overlays P1
        u16* wts = (u16*)(w + 50331648);
        u16 *wt1h = wts,            *wt1l = wt1h + 32768;
        u16 *wt2h = wt1l + 32768,   *wt2l = wt2h + 131072;
        u16 *wt3h = wt2l + 131072,  *wt3l = wt3h + 524288;
        u16 *wd1h = wt3l + 524288,  *wd1l = wd1h + 524288;
        u16 *wd2h = wd1l + 524288,  *wd2l = wd2h + 131072;
        u16 *wd3h = wd2l + 131072,  *wd3l = wd3h + 32768;
        char* cs = w + 55836672;
        int*   deg     = (int*)cs;
        int*   rowptr  = deg + N_NODES;
        int*   pos     = rowptr + 8256;
        float* dinv    = (float*)(pos + N_NODES);
        int*   csr_src = (int*)(dinv + N_NODES);
        float* csr_w   = (float*)(csr_src + N_EDGES);

        // merged weight prep + deg zeroing (must precede k_count)
        k_prep_all<<<1376256 / 256, 256, 0, stream>>>(g1w, g2w, g3w, d1w, d2w, d3w, wts, deg);

        // CSR build
        k_count<<<N_EDGES / 256, 256, 0, stream>>>(ei, deg);
        k_scan<<<1, 1024, 0, stream>>>(deg, rowptr, pos, dinv);
        k_fill<<<N_EDGES / 256, 256, 0, stream>>>(ei, dinv, pos, csr_src, csr_w);

        // fused encoder
        k_enc_fused<<<N_NODES / 4, 256, 0, stream>>>(x, w1, b1, w2, b2, w3, b3, p0hi, p0lo);

        // gcn1: agg(128) then 128->256
        k_agg_s<128><<<N_NODES / 4, 256, 0, stream>>>(p0hi, p0lo, p1hi, p1lo, rowptr, csr_src, csr_w, dinv);
        k_gemm_mfma<1><<<dim3(256 / 128, N_NODES / 128), 256, 0, stream>>>(
            p1hi, p1lo, wt1h, wt1l, g1b, nullptr, p0hi, p0lo, N_NODES, 256, 128, 1);
        // gcn2: agg(256) then 256->512
        k_agg_s<256><<<N_NODES / 4, 256, 0, stream>>>(p0hi, p0lo, p1hi, p1lo, rowptr, csr_src, csr_w, dinv);
        k_gemm_mfma<1><<<dim3(512 / 128, N_NODES / 128), 256, 0, stream>>>(
            p1hi, p1lo, wt2h, wt2l, g2b, nullptr, p0hi, p0lo, N_NODES, 512, 256, 1);
        // gcn3: agg(512) then 512->1024
        k_agg_s<512><<<N_NODES / 4, 256, 0, stream>>>(p0hi, p0lo, p1hi, p1lo, rowptr, csr_src, csr_w, dinv);
        k_gemm_mfma<1><<<dim3(1024 / 128, N_NODES / 128), 256, 0, stream>>>(
            p1hi, p1lo, wt3h, wt3l, g3b, nullptr, p0hi, p0lo, N_NODES, 1024, 512, 1);
        // decoder
        k_gemm_mfma<1><<<dim3(512 / 128, N_NODES / 128), 256, 0, stream>>>(
            p0hi, p0lo, wd1h, wd1l, d1b, nullptr, p1hi, p1lo, N_NODES, 512, 1024, 1);
        k_gemm_mfma<1><<<dim3(256 / 128, N_NODES / 128), 256, 0, stream>>>(
            p1hi, p1lo, wd2h, wd2l, d2b, nullptr, p0hi, p0lo, N_NODES, 256, 512, 1);
        k_gemm_mfma<0><<<dim3(128 / 128, N_NODES / 128), 256, 0, stream>>>(
            p0hi, p0lo, wd3h, wd3l, d3b, f0, nullptr, nullptr, N_NODES, 128, 256, 1);

        // fused d4 + softmax
        k_d4sm_fused<<<N_NODES / 4, 256, 0, stream>>>(f0, d4w, d4b, out);
    } else {
        // ---- fallback: fp32 path ----
        float* bufA = (float*)d_ws;
        float* bufB = bufA + (size_t)N_NODES * 1024;
        int*   deg     = (int*)(bufB + (size_t)N_NODES * 512);
        int*   rowptr  = deg + N_NODES;
        int*   pos     = rowptr + 8256;
        float* dinv    = (float*)(pos + N_NODES);
        int*   csr_src = (int*)(dinv + N_NODES);
        float* csr_w   = (float*)(csr_src + N_EDGES);

        hipMemsetAsync(deg, 0, N_NODES * sizeof(int), stream);
        k_count<<<N_EDGES / 256, 256, 0, stream>>>(ei, deg);
        k_scan<<<1, 1024, 0, stream>>>(deg, rowptr, pos, dinv);
        k_fill<<<N_EDGES / 256, 256, 0, stream>>>(ei, dinv, pos, csr_src, csr_w);

        k_linear_small<0><<<dim3(1, N_NODES), 64, 0, stream>>>(x,    w1, b1, bufA, nullptr, nullptr, 3, 32, 1);
        k_linear_small<0><<<dim3(1, N_NODES), 64, 0, stream>>>(bufA, w2, b2, bufB, nullptr, nullptr, 32, 64, 1);
        k_linear_small<0><<<dim3(2, N_NODES), 64, 0, stream>>>(bufB, w3, b3, bufA, nullptr, nullptr, 64, 128, 1);

        k_agg<128><<<N_NODES / 4, 256, 0, stream>>>(bufA, bufB, rowptr, csr_src, csr_w, dinv);
        k_gemm<64, 64, 16, 4, 4><<<dim3(256 / 64, N_NODES / 64), 256, 0, stream>>>(
            bufB, g1w, g1b, bufA, N_NODES, 256, 128, 1);
        k_agg<256><<<N_NODES / 4, 256, 0, stream>>>(bufA, bufB, rowptr, csr_src, csr_w, dinv);
        k_gemm<128, 128, 16, 8, 8><<<dim3(512 / 128, N_NODES / 128), 256, 0, stream>>>(
            bufB, g2w, g2b, bufA, N_NODES, 512, 256, 1);
        k_agg<512><<<N_NODES / 4, 256, 0, stream>>>(bufA, bufB, rowptr, csr_src, csr_w, dinv);
        k_gemm<128, 128, 16, 8, 8><<<dim3(1024 / 128, N_NODES / 128), 256, 0, stream>>>(
            bufB, g3w, g3b, bufA, N_NODES, 1024, 512, 1);
        k_gemm<128, 128, 16, 8, 8><<<dim3(512 / 128, N_NODES / 128), 256, 0, stream>>>(
            bufA, d1w, d1b, bufB, N_NODES, 512, 1024, 1);
        k_gemm<64, 64, 16, 4, 4><<<dim3(256 / 64, N_NODES / 64), 256, 0, stream>>>(
            bufB, d2w, d2b, bufA, N_NODES, 256, 512, 1);
        k_gemm<64, 64, 16, 4, 4><<<dim3(128 / 64, N_NODES / 64), 256, 0, stream>>>(
            bufA, d3w, d3b, bufB, N_NODES, 128, 256, 1);
        k_linear_small<0><<<dim3(1, N_NODES), 64, 0, stream>>>(bufB, d4w, d4b, bufA, nullptr, nullptr, 128, 50, 0);
        k_softmax50<<<N_NODES / 4, 256, 0, stream>>>(bufA, out);
    }
}